// Round 6
// baseline (3963.783 us; speedup 1.0000x reference)
//
#include <hip/hip_runtime.h>
#include <math.h>

// MD-LSTM, 32x32 grid, B=128, HID=256, gates=1024.
// Diagonal wavefront: 63 launches; cells on diag d depend only on diag d-1.
//
// ACCURACY: whole recurrence in fp64 (fp32 trajectories diverge past the
// 1.945e-2 threshold). GEMM on v_mfma_f64_16x16x4f64; D-fragment layout
// probed at runtime (R2/R5 passed => probe resolves correctly on HW).
//
// R5 counters: MfmaUtil 31-34% (= the 27us f64-matrix floor of an 80us
// dispatch), FETCH 30MB (~unique state: XCD A-locality works), but
// SQ_LDS_BANK_CONFLICT still 3M/dispatch: the G-LDS round trip (D-frag
// scatter + epilogue gather, both 4-way conflicted) + 2 barriers.
//
// R6: ELIMINATE the G round trip. Wave remap: wave = (wb0 16-b) x (wj0
// 16-j); its 4 MFMA f-tiles are the 4 GATES at the same 16 j-columns.
// The D-fragment then already holds all 4 gates for the same (b,k) in
// registers -> epilogue is direct from acc: no G_lds, no scatter/gather,
// 2 fewer barriers. The freed ck==7 prefetch slot loads the epilogue
// operands (x, s_up, s_left) under the last chunk's MFMA block.
//
// Block = (cell, b-quarter(32), ktile(32 gate cols x 4 gates));
// XCD A-locality: id = (g%8) + 8*((g/8)*8 + ktile), g=(cell,b4) group;
// all 8 ktile-blocks of a group land on one XCD -> A-panel in one L2.
//
// LDS (26.6 KB):
//   A[k=32][rotRow=32] f64 (rot (row+k)&31, conflict-free MFMA reads)
//   W[phi=128][36] f32 (+4 pad; staging ds_write_b128 bank-uniform)

#define HIMG 32
#define WIMG 32
#define BATCH 128
#define HID 256
#define BH (BATCH * HID)
#define SLAB (32 * 128 * 256)

#define PSTR 36  // floats per phi-row of W_lds (32 + 4 pad)

typedef double f64x4 __attribute__((ext_vector_type(4)));

__global__ __launch_bounds__(256, 4)
void mdlstm_diag_kernel(const float* __restrict__ x,
                        const float* __restrict__ wih,
                        const float* __restrict__ whh,
                        const float* __restrict__ bias,
                        float* __restrict__ out,
                        double* __restrict__ hbuf,   // [2][32][128][256]
                        double* __restrict__ sbuf,   // [2][32][128][256]
                        int d, int rlo, int nc)
{
    __shared__ double lds[3328];             // 26.6 KB
    double* A_lds = lds;                     // [k=32][rot=32]     8 KB
    float*  W_lds = (float*)(lds + 1024);    // [phi=128][PSTR=36] 18 KB

    const int tid = threadIdx.x;
    const int id  = blockIdx.x;

    // ---- XCD-locality decode: id = (g%8) + 8*((g/8)*8 + ktile) ----
    const int rx    = id & 7;
    const int q     = id >> 3;
    const int ktile = q & 7;
    const int ghi   = q >> 3;
    const int g     = ghi * 8 + rx;          // group = cell*4 + b4
    if (g >= nc * 4) return;                 // padded grid tail
    const int cellIdx = g >> 2;
    const int b4      = g & 3;
    const int k0 = ktile * 32;
    const int b0 = b4 * 32;

    const int r = rlo + cellIdx;
    const int c = d - r;
    const int rc = r * WIMG + c;

    const int prev = (d & 1) ^ 1;
    const int cur  = d & 1;
    const double* hp = hbuf + (size_t)prev * SLAB;
    const double* sp = sbuf + (size_t)prev * SLAB;
    double* hc = hbuf + (size_t)cur * SLAB;
    double* sc = sbuf + (size_t)cur * SLAB;

    const bool has_up   = (r > 0);
    const bool has_left = (c > 0);
    const double* hu = hp + (size_t)(r - 1) * BH;  // valid iff has_up
    const double* hl = hp + (size_t)r * BH;        // valid iff has_left

    // ---- wave / lane geometry ----
    const int lane = tid & 63;
    const int wid  = tid >> 6;
    const int wb0  = (wid & 1) * 16;         // wave's batch offset in block
    const int wj0  = (wid >> 1) * 16;        // wave's j (gate-col) offset
    const int cc   = lane & 15;
    const int gg   = lane >> 4;

    // ---- D-layout probe (one MFMA; distinguishes 4 candidate mappings) ----
    int layout;
    {
        double pa = (cc == 1) ? 1.0 : 0.0;
        double pb = (cc == 2) ? 1.0 : 0.0;
        f64x4 pc = {0.0, 0.0, 0.0, 0.0};
        pc = __builtin_amdgcn_mfma_f64_16x16x4f64(pa, pb, pc, 0, 0, 0);
        double s = fabs(pc[0]) + fabs(pc[1]) + fabs(pc[2]) + fabs(pc[3]);
        #pragma unroll
        for (int off = 32; off > 0; off >>= 1) s += __shfl_xor(s, off, 64);
        unsigned long long h0 = __ballot(lane == 2  && pc[1] == 4.0);
        unsigned long long h1 = __ballot(lane == 18 && pc[0] == 4.0);
        unsigned long long h2 = __ballot(lane == 1  && pc[2] == 4.0);
        unsigned long long h3 = __ballot(lane == 33 && pc[0] == 4.0);
        layout = -1;
        if (s == 4.0) {
            if (h0) layout = 0;
            else if (h1) layout = 1;
            else if (h2) layout = 2;
            else if (h3) layout = 3;
        }
    }
    const bool use_mfma = (layout >= 0);
    const int slay = use_mfma ? layout : 0;

    // ---- staging maps ----
    const int a_row = tid >> 4;
    const int a_kp  = tid & 15;
    const size_t ga0 = (size_t)(b0 + a_row) * HID + 2 * a_kp;
    const size_t ga1 = ga0 + (size_t)16 * HID;
    // W: p in 0..3: u=tid+p*256; phi=u>>3 (0..127 = g*32+j), kq=u&7.
    const float* w_src[4];
    int w_pos[4];
    #pragma unroll
    for (int p = 0; p < 4; p++) {
        int u = tid + p * 256;
        int phi = u >> 3, kq = u & 7;
        int F = (phi >> 5) * 256 + k0 + (phi & 31);   // global gate row
        w_src[p] = whh + (size_t)F * HID + 4 * kq;
        w_pos[p] = phi * PSTR + 4 * kq;               // LDS float index
    }

    f64x4 acc[4];                            // acc[gate][reg]
    #pragma unroll
    for (int gt = 0; gt < 4; gt++) acc[gt] = (f64x4){0.0, 0.0, 0.0, 0.0};

    // ---- prefetch chunk 0 ----
    double2 pu0, pu1, pl0, pl1;
    float4 pw[4];
    {
        const double2 z = {0.0, 0.0};
        pu0 = has_up   ? *(const double2*)(hu + ga0) : z;
        pu1 = has_up   ? *(const double2*)(hu + ga1) : z;
        pl0 = has_left ? *(const double2*)(hl + ga0) : z;
        pl1 = has_left ? *(const double2*)(hl + ga1) : z;
        #pragma unroll
        for (int p = 0; p < 4; p++)
            pw[p] = *(const float4*)(w_src[p]);
    }

    const float* wbase = &W_lds[(wj0 + cc) * PSTR + gg];  // + gt*32*PSTR + 4t

    // ---- epilogue prefetch registers (filled during last chunk) ----
    const int kFast = k0 + wj0 + cc;         // k for layouts 0/1 (n = cc)
    double xpr[4], sur[4], slr[4];

    for (int ck = 0; ck < 8; ck++) {
        __syncthreads();                  // previous compute done reading LDS
        {
            const int k = 2 * a_kp;
            const double s0x = pu0.x + pl0.x, s0y = pu0.y + pl0.y;
            const double s1x = pu1.x + pl1.x, s1y = pu1.y + pl1.y;
            A_lds[ k      * 32 + ((a_row      + k    ) & 31)] = s0x;
            A_lds[(k + 1) * 32 + ((a_row      + k + 1) & 31)] = s0y;
            A_lds[ k      * 32 + ((a_row + 16 + k    ) & 31)] = s1x;
            A_lds[(k + 1) * 32 + ((a_row + 16 + k + 1) & 31)] = s1y;
        }
        #pragma unroll
        for (int p = 0; p < 4; p++)
            *(float4*)&W_lds[w_pos[p]] = pw[p];   // b128, conflict-free
        __syncthreads();                  // LDS ready

        if (ck < 7) {                     // prefetch next chunk during compute
            const int kg = (ck + 1) * 32;
            const double2 z = {0.0, 0.0};
            pu0 = has_up   ? *(const double2*)(hu + ga0 + kg) : z;
            pu1 = has_up   ? *(const double2*)(hu + ga1 + kg) : z;
            pl0 = has_left ? *(const double2*)(hl + ga0 + kg) : z;
            pl1 = has_left ? *(const double2*)(hl + ga1 + kg) : z;
            #pragma unroll
            for (int p = 0; p < 4; p++)
                pw[p] = *(const float4*)(w_src[p] + kg);
        } else if (slay < 2) {
            // epilogue operand prefetch under the last MFMA block
            #pragma unroll
            for (int rg = 0; rg < 4; rg++) {
                const int m = (slay == 0) ? (4 * gg + rg) : (gg + 4 * rg);
                const int b = b0 + wb0 + m;
                xpr[rg] = (double)x[b * (HIMG * WIMG) + rc];
                sur[rg] = has_up   ? sp[(size_t)(r - 1) * BH + b * HID + kFast] : 0.0;
                slr[rg] = has_left ? sp[(size_t)r * BH + b * HID + kFast]       : 0.0;
            }
        }

        if (use_mfma) {
            // ---- MFMA inner loop: 8 k-steps x 4 gates ----
            #pragma unroll
            for (int t = 0; t < 8; t++) {
                const int kq = t * 4 + gg;
                const double aval = A_lds[kq * 32 + ((wb0 + cc + kq) & 31)];
                #pragma unroll
                for (int gt = 0; gt < 4; gt++) {
                    const double bval = (double)wbase[gt * (32 * PSTR) + 4 * t];
                    acc[gt] = __builtin_amdgcn_mfma_f64_16x16x4f64(aval, bval, acc[gt], 0, 0, 0);
                }
            }
        } else {
            // ---- VALU fallback (layout-0 mapping: m=4*gg+rg, n=cc) ----
            for (int k = 0; k < 32; k++) {
                double av[4], wv4[4];
                #pragma unroll
                for (int rg = 0; rg < 4; rg++)
                    av[rg] = A_lds[k * 32 + ((wb0 + 4 * gg + rg + k) & 31)];
                #pragma unroll
                for (int gt = 0; gt < 4; gt++)
                    wv4[gt] = (double)W_lds[(gt * 32 + wj0 + cc) * PSTR + k];
                #pragma unroll
                for (int gt = 0; gt < 4; gt++)
                    #pragma unroll
                    for (int rg = 0; rg < 4; rg++)
                        acc[gt][rg] = fma(av[rg], wv4[gt], acc[gt][rg]);
            }
        }
    }

    // ---- direct epilogue from D-fragments (all fp64, no LDS round trip) ----
    if (slay < 2) {
        double wv[4], bv[4];
        #pragma unroll
        for (int gt = 0; gt < 4; gt++) {
            wv[gt] = (double)wih[gt * 256 + kFast];
            bv[gt] = (double)bias[gt * 256 + kFast];
        }
        #pragma unroll
        for (int rg = 0; rg < 4; rg++) {
            const int m = (slay == 0) ? (4 * gg + rg) : (gg + 4 * rg);
            const int b = b0 + wb0 + m;
            const double gi = acc[0][rg] + xpr[rg] * wv[0] + bv[0];
            const double gf = acc[1][rg] + xpr[rg] * wv[1] + bv[1];
            const double gG = acc[2][rg] + xpr[rg] * wv[2] + bv[2];
            const double go = acc[3][rg] + xpr[rg] * wv[3] + bv[3];
            const double iv = 1.0 / (1.0 + exp(-gi));
            const double fv = 1.0 / (1.0 + exp(-gf));
            const double gv = tanh(gG);
            const double ov = 1.0 / (1.0 + exp(-go));
            const double sv = fv * (sur[rg] + slr[rg]) + iv * gv;
            const double hv = ov * tanh(sv);
            sc[(size_t)r * BH + b * HID + kFast] = sv;
            hc[(size_t)r * BH + b * HID + kFast] = hv;
            out[(size_t)b * (HIMG * WIMG * HID) + (size_t)rc * HID + kFast] = (float)hv;
        }
    } else {
        // transposed D layouts: b = cc-row, k varies per reg
        const int b = b0 + wb0 + cc;
        const double xp = (double)x[b * (HIMG * WIMG) + rc];
        #pragma unroll
        for (int rg = 0; rg < 4; rg++) {
            const int n = (slay == 2) ? (4 * gg + rg) : (gg + 4 * rg);
            const int kE = k0 + wj0 + n;
            const double su = has_up   ? sp[(size_t)(r - 1) * BH + b * HID + kE] : 0.0;
            const double sl = has_left ? sp[(size_t)r * BH + b * HID + kE]       : 0.0;
            const double gi = acc[0][rg] + xp * (double)wih[0 * 256 + kE] + (double)bias[0 * 256 + kE];
            const double gf = acc[1][rg] + xp * (double)wih[1 * 256 + kE] + (double)bias[1 * 256 + kE];
            const double gG = acc[2][rg] + xp * (double)wih[2 * 256 + kE] + (double)bias[2 * 256 + kE];
            const double go = acc[3][rg] + xp * (double)wih[3 * 256 + kE] + (double)bias[3 * 256 + kE];
            const double iv = 1.0 / (1.0 + exp(-gi));
            const double fv = 1.0 / (1.0 + exp(-gf));
            const double gv = tanh(gG);
            const double ov = 1.0 / (1.0 + exp(-go));
            const double sv = fv * (su + sl) + iv * gv;
            const double hv = ov * tanh(sv);
            sc[(size_t)r * BH + b * HID + kE] = sv;
            hc[(size_t)r * BH + b * HID + kE] = hv;
            out[(size_t)b * (HIMG * WIMG * HID) + (size_t)rc * HID + kE] = (float)hv;
        }
    }
}

extern "C" void kernel_launch(void* const* d_in, const int* in_sizes, int n_in,
                              void* d_out, int out_size, void* d_ws, size_t ws_size,
                              hipStream_t stream) {
    const float* x    = (const float*)d_in[0];   // (128, 1024)
    const float* wih  = (const float*)d_in[1];   // (1024, 1)
    const float* whh  = (const float*)d_in[2];   // (1024, 256)
    const float* bias = (const float*)d_in[3];   // (1024,)
    float* out = (float*)d_out;                  // (128, 32*32*256)

    double* hbuf = (double*)d_ws;                // [2][32][128][256] dbl
    double* sbuf = hbuf + (size_t)2 * SLAB;      // ws usage ~33.6 MB

    for (int d = 0; d < HIMG + WIMG - 1; d++) {
        int rlo = d - (WIMG - 1); if (rlo < 0) rlo = 0;
        int rhi = d < (HIMG - 1) ? d : (HIMG - 1);
        int nc = rhi - rlo + 1;
        int g8 = (4 * nc + 7) / 8;               // padded group-octets
        mdlstm_diag_kernel<<<dim3(g8 * 64), 256, 0, stream>>>(
            x, wih, whh, bias, out, hbuf, sbuf, d, rlo, nc);
    }
}

// Round 7
// 3304.192 us; speedup vs baseline: 1.1996x; 1.1996x over previous
//
#include <hip/hip_runtime.h>
#include <math.h>

// MD-LSTM, 32x32 grid, B=128, HID=256, gates=1024.
// Diagonal wavefront: 63 launches; cells on diag d depend only on diag d-1.
//
// ACCURACY: whole recurrence in fp64 (fp32 trajectories diverge past the
// 1.945e-2 threshold). GEMM on v_mfma_f64_16x16x4f64; D-fragment layout
// probed at runtime (R2/R5/R6 passed => probe resolves correctly on HW).
//
// R6 post-mortem: direct-from-AGPR epilogue halved global segment sizes
// (256B->128B state, 128B->64B out) and FETCH/WRITE both DOUBLED ->
// dur 80->93us. Bank conflicts (~3M) are <2% of SIMD cycles — never the
// bottleneck. REVERTED to R5's G-LDS epilogue + 32-contiguous access.
//
// R5 decomposition: T(nc) = 19.6us + 1.89us*nc. Fixed part = launch ramp
// + per-block serial path: 8 chunks x (stage -> barrier -> MFMA -> barrier).
// R7: LDS DOUBLE-BUFFER with ONE barrier per chunk (18 -> 10 barriers;
// staging writes of ck+1 overlap MFMA of ck). Race-safe: a wave at
// barrier(ck) has consumed its buf[ck^1] reads into registers, so writes
// to buf[ck^1] by fast waves after that barrier cannot race. Epilogue
// operands (x, s_up, s_left) issued at ck==7 under the last MFMA block,
// with R5's 32-contiguous addressing.
//
// Block = (cell, b-quarter(32), ktile(32 gate cols x 4 gates));
// XCD A-locality: id = (g%8) + 8*((g/8)*8 + ktile), g=(cell,b4) group;
// all 8 ktile-blocks of a group land on one XCD -> A-panel in one L2.
//
// LDS 53248 B total (3 blocks/CU = 159.7KB <= 160KB):
//   buf p (p=0,1) at p*3328 dbl: A[k=32][rot32] f64 (8KB) then
//     W[phi=128][PSTR=36] f32 (18.4KB)  (rot slot (row+k)&31;
//     W staging = 1 ds_write_b128/thread, bank-uniform)
//   G[phi=128][rot32] f64 (32KB) unioned at offset 0 after the K-loop
//     (overlaps buf1's A region -> keep the pre-scatter barrier).

#define HIMG 32
#define WIMG 32
#define BATCH 128
#define HID 256
#define BH (BATCH * HID)
#define SLAB (32 * 128 * 256)

#define PSTR 36    // floats per phi-row of W_lds (32 + 4 pad)
#define BUFD 3328  // doubles per LDS buffer (1024 A + 2304 W-as-dbl)

typedef double f64x4 __attribute__((ext_vector_type(4)));

__global__ __launch_bounds__(256, 4)
void mdlstm_diag_kernel(const float* __restrict__ x,
                        const float* __restrict__ wih,
                        const float* __restrict__ whh,
                        const float* __restrict__ bias,
                        float* __restrict__ out,
                        double* __restrict__ hbuf,   // [2][32][128][256]
                        double* __restrict__ sbuf,   // [2][32][128][256]
                        int d, int rlo, int nc)
{
    __shared__ double lds[2 * BUFD];         // 53248 B
    double* G_lds = lds;                     // [phi=128][rot=32] 32 KB (post-loop)

    const int tid = threadIdx.x;
    const int id  = blockIdx.x;

    // ---- XCD-locality decode: id = (g%8) + 8*((g/8)*8 + ktile) ----
    const int rx    = id & 7;
    const int q     = id >> 3;
    const int ktile = q & 7;
    const int ghi   = q >> 3;
    const int g     = ghi * 8 + rx;          // group = cell*4 + b4
    if (g >= nc * 4) return;                 // padded grid tail
    const int cellIdx = g >> 2;
    const int b4      = g & 3;
    const int k0 = ktile * 32;
    const int b0 = b4 * 32;

    const int r = rlo + cellIdx;
    const int c = d - r;
    const int rc = r * WIMG + c;

    const int prev = (d & 1) ^ 1;
    const int cur  = d & 1;
    const double* hp = hbuf + (size_t)prev * SLAB;
    const double* sp = sbuf + (size_t)prev * SLAB;
    double* hc = hbuf + (size_t)cur * SLAB;
    double* sc = sbuf + (size_t)cur * SLAB;

    const bool has_up   = (r > 0);
    const bool has_left = (c > 0);
    const double* hu = hp + (size_t)(r - 1) * BH;  // valid iff has_up
    const double* hl = hp + (size_t)r * BH;        // valid iff has_left

    // ---- wave / lane geometry ----
    const int lane = tid & 63;
    const int wid  = tid >> 6;
    const int wb0  = (wid & 1) * 16;         // wave's batch offset in block
    const int wf0  = (wid >> 1) * 64;        // wave's phi offset in block
    const int cc   = lane & 15;
    const int gg   = lane >> 4;

    // ---- D-layout probe (one MFMA; distinguishes 4 candidate mappings) ----
    int layout;
    {
        double pa = (cc == 1) ? 1.0 : 0.0;
        double pb = (cc == 2) ? 1.0 : 0.0;
        f64x4 pc = {0.0, 0.0, 0.0, 0.0};
        pc = __builtin_amdgcn_mfma_f64_16x16x4f64(pa, pb, pc, 0, 0, 0);
        double s = fabs(pc[0]) + fabs(pc[1]) + fabs(pc[2]) + fabs(pc[3]);
        #pragma unroll
        for (int off = 32; off > 0; off >>= 1) s += __shfl_xor(s, off, 64);
        unsigned long long h0 = __ballot(lane == 2  && pc[1] == 4.0);
        unsigned long long h1 = __ballot(lane == 18 && pc[0] == 4.0);
        unsigned long long h2 = __ballot(lane == 1  && pc[2] == 4.0);
        unsigned long long h3 = __ballot(lane == 33 && pc[0] == 4.0);
        layout = -1;
        if (s == 4.0) {
            if (h0) layout = 0;
            else if (h1) layout = 1;
            else if (h2) layout = 2;
            else if (h3) layout = 3;
        }
    }
    const bool use_mfma = (layout >= 0);

    // ---- staging maps ----
    const int a_row = tid >> 4;
    const int a_kp  = tid & 15;
    const size_t ga0 = (size_t)(b0 + a_row) * HID + 2 * a_kp;
    const size_t ga1 = ga0 + (size_t)16 * HID;
    // W: p in 0..3: u=tid+p*256; phi=u>>3 (0..127 = g*32+j), kq=u&7.
    const float* w_src[4];
    int w_pos[4];
    #pragma unroll
    for (int p = 0; p < 4; p++) {
        int u = tid + p * 256;
        int phi = u >> 3, kq = u & 7;
        int F = (phi >> 5) * 256 + k0 + (phi & 31);   // global gate row
        w_src[p] = whh + (size_t)F * HID + 4 * kq;
        w_pos[p] = phi * PSTR + 4 * kq;               // LDS float index
    }

    // ---- epilogue geometry (loads issued at ck==7) ----
    const int ec = tid & 31;              // k-col within ktile (32-contig!)
    const int eb = tid >> 5;              // 0..7
    const int kE = k0 + ec;
    double xp4[4], su4[4], sl4[4];

    f64x4 acc[4];
    #pragma unroll
    for (int ft = 0; ft < 4; ft++) acc[ft] = (f64x4){0.0, 0.0, 0.0, 0.0};

    // ---- prefetch chunk 0 ----
    double2 pu0, pu1, pl0, pl1;
    float4 pw[4];
    {
        const double2 z = {0.0, 0.0};
        pu0 = has_up   ? *(const double2*)(hu + ga0) : z;
        pu1 = has_up   ? *(const double2*)(hu + ga1) : z;
        pl0 = has_left ? *(const double2*)(hl + ga0) : z;
        pl1 = has_left ? *(const double2*)(hl + ga1) : z;
        #pragma unroll
        for (int p = 0; p < 4; p++)
            pw[p] = *(const float4*)(w_src[p]);
    }

    for (int ck = 0; ck < 8; ck++) {
        double* A_l = lds + (ck & 1) * BUFD;
        float*  W_l = (float*)(lds + (ck & 1) * BUFD + 1024);

        // ---- stage chunk ck into buf[ck&1] (overlaps prior MFMA) ----
        {
            const int k = 2 * a_kp;
            const double s0x = pu0.x + pl0.x, s0y = pu0.y + pl0.y;
            const double s1x = pu1.x + pl1.x, s1y = pu1.y + pl1.y;
            A_l[ k      * 32 + ((a_row      + k    ) & 31)] = s0x;
            A_l[(k + 1) * 32 + ((a_row      + k + 1) & 31)] = s0y;
            A_l[ k      * 32 + ((a_row + 16 + k    ) & 31)] = s1x;
            A_l[(k + 1) * 32 + ((a_row + 16 + k + 1) & 31)] = s1y;
        }
        #pragma unroll
        for (int p = 0; p < 4; p++)
            *(float4*)&W_l[w_pos[p]] = pw[p];     // b128, bank-uniform
        __syncthreads();                  // buf[ck&1] ready (single barrier)

        if (ck < 7) {                     // prefetch next chunk during compute
            const int kg = (ck + 1) * 32;
            const double2 z = {0.0, 0.0};
            pu0 = has_up   ? *(const double2*)(hu + ga0 + kg) : z;
            pu1 = has_up   ? *(const double2*)(hu + ga1 + kg) : z;
            pl0 = has_left ? *(const double2*)(hl + ga0 + kg) : z;
            pl1 = has_left ? *(const double2*)(hl + ga1 + kg) : z;
            #pragma unroll
            for (int p = 0; p < 4; p++)
                pw[p] = *(const float4*)(w_src[p] + kg);
        } else {
            // epilogue operand loads under the last MFMA block
            #pragma unroll
            for (int i = 0; i < 4; i++) {
                const int b = b0 + eb + 8 * i;
                xp4[i] = (double)x[b * (HIMG * WIMG) + rc];
                su4[i] = has_up   ? sp[(size_t)(r - 1) * BH + b * HID + kE] : 0.0;
                sl4[i] = has_left ? sp[(size_t)r * BH + b * HID + kE]       : 0.0;
            }
        }

        if (use_mfma) {
            // ---- MFMA inner loop: 8 k-steps x 4 f-tiles ----
            const float* wbase = &W_l[(wf0 + cc) * PSTR + gg];
            #pragma unroll
            for (int t = 0; t < 8; t++) {
                const int kq = t * 4 + gg;
                const double aval = A_l[kq * 32 + ((wb0 + cc + kq) & 31)];
                #pragma unroll
                for (int ft = 0; ft < 4; ft++) {
                    const double bval = (double)wbase[ft * (16 * PSTR) + 4 * t];
                    acc[ft] = __builtin_amdgcn_mfma_f64_16x16x4f64(aval, bval, acc[ft], 0, 0, 0);
                }
            }
        } else {
            // ---- VALU fallback (row=wb0+4*gg+b, col=cc) ----
            for (int k = 0; k < 32; k++) {
                double av[4], wv4[4];
                #pragma unroll
                for (int b = 0; b < 4; b++)
                    av[b] = A_l[k * 32 + ((wb0 + 4 * gg + b + k) & 31)];
                #pragma unroll
                for (int ft = 0; ft < 4; ft++)
                    wv4[ft] = (double)W_l[(wf0 + ft * 16 + cc) * PSTR + k];
                #pragma unroll
                for (int ft = 0; ft < 4; ft++)
                    #pragma unroll
                    for (int b = 0; b < 4; b++)
                        acc[ft][b] = fma(av[b], wv4[ft], acc[ft][b]);
            }
        }
    }

    // ---- gates -> LDS (layout-generic D-frag scatter; rot swizzle) ----
    __syncthreads();                      // all MFMA reads done (G overlaps bufs)
    const int slay = use_mfma ? layout : 0;
    #pragma unroll
    for (int ft = 0; ft < 4; ft++) {
        #pragma unroll
        for (int b = 0; b < 4; b++) {
            const int rA = (slay & 1) ? (gg + 4 * b) : (4 * gg + b);
            const int m  = (slay >= 2) ? cc : rA;   // local batch row
            const int n  = (slay >= 2) ? rA : cc;   // local phi
            const int phi  = wf0 + ft * 16 + n;
            const int brow = wb0 + m;
            G_lds[phi * 32 + ((brow + phi) & 31)] = acc[ft][b];
        }
    }
    __syncthreads();

    // ---- fused epilogue (all fp64; 32-contiguous global access) ----
    double wv[4], bv[4];
    #pragma unroll
    for (int g2 = 0; g2 < 4; g2++) {
        wv[g2] = (double)wih[g2 * 256 + kE];
        bv[g2] = (double)bias[g2 * 256 + kE];
    }
    #pragma unroll
    for (int i = 0; i < 4; i++) {
        const int bl = eb + 8 * i;
        const int b = b0 + bl;
        double gate[4];
        #pragma unroll
        for (int g2 = 0; g2 < 4; g2++) {
            const int phi = g2 * 32 + ec;
            gate[g2] = G_lds[phi * 32 + ((bl + phi) & 31)];
        }
        const double gi = gate[0] + xp4[i] * wv[0] + bv[0];
        const double gf = gate[1] + xp4[i] * wv[1] + bv[1];
        const double gG = gate[2] + xp4[i] * wv[2] + bv[2];
        const double go = gate[3] + xp4[i] * wv[3] + bv[3];
        const double iv = 1.0 / (1.0 + exp(-gi));
        const double fv = 1.0 / (1.0 + exp(-gf));
        const double gv = tanh(gG);
        const double ov = 1.0 / (1.0 + exp(-go));
        const double sv = fv * (su4[i] + sl4[i]) + iv * gv;
        const double hv = ov * tanh(sv);
        sc[(size_t)r * BH + b * HID + kE] = sv;
        hc[(size_t)r * BH + b * HID + kE] = hv;
        out[(size_t)b * (HIMG * WIMG * HID) + (size_t)rc * HID + kE] = (float)hv;
    }
}

extern "C" void kernel_launch(void* const* d_in, const int* in_sizes, int n_in,
                              void* d_out, int out_size, void* d_ws, size_t ws_size,
                              hipStream_t stream) {
    const float* x    = (const float*)d_in[0];   // (128, 1024)
    const float* wih  = (const float*)d_in[1];   // (1024, 1)
    const float* whh  = (const float*)d_in[2];   // (1024, 256)
    const float* bias = (const float*)d_in[3];   // (1024,)
    float* out = (float*)d_out;                  // (128, 32*32*256)

    double* hbuf = (double*)d_ws;                // [2][32][128][256] dbl
    double* sbuf = hbuf + (size_t)2 * SLAB;      // ws usage ~33.6 MB

    for (int d = 0; d < HIMG + WIMG - 1; d++) {
        int rlo = d - (WIMG - 1); if (rlo < 0) rlo = 0;
        int rhi = d < (HIMG - 1) ? d : (HIMG - 1);
        int nc = rhi - rlo + 1;
        int g8 = (4 * nc + 7) / 8;               // padded group-octets
        mdlstm_diag_kernel<<<dim3(g8 * 64), 256, 0, stream>>>(
            x, wih, whh, bias, out, hbuf, sbuf, d, rlo, nc);
    }
}